// Round 1
// baseline (138.952 us; speedup 1.0000x reference)
//
#include <hip/hip_runtime.h>
#include <math.h>

// ---------------------------------------------------------------------------
// AUV Fossen 6-DOF RK2 step, K independent states of 13 floats.
// Memory-bound: 128 B/elem -> 67 MB total; target ~11 us main kernel.
// ---------------------------------------------------------------------------

struct SC {                 // per-block LDS copy of the tiny shared constants
    float M[36];            // mTot
    float Mi[36];           // inv(mTot), precomputed by invert6x6 into d_ws
    float LD[36];           // linDamp
    float LDF[36];          // linDampFow
    float QD[6];            // diag(quadDamp) -- only diag survives (*eye6)
    float cog[3];
    float cob[3];
    float mass;
    float vol;
};

__device__ __forceinline__ void fossen_dot(const float* __restrict__ X,
                                           const float* __restrict__ U,
                                           const SC& c,
                                           float* __restrict__ xd)
{
    const float qx = X[3], qy = X[4], qz = X[5], qw = X[6];
    // body->inertial rotation from quaternion (x,y,z,w)
    const float r00 = 1.f - 2.f*(qy*qy + qz*qz);
    const float r01 = 2.f*(qx*qy - qz*qw);
    const float r02 = 2.f*(qx*qz + qy*qw);
    const float r10 = 2.f*(qx*qy + qz*qw);
    const float r11 = 1.f - 2.f*(qx*qx + qz*qz);
    const float r12 = 2.f*(qy*qz - qx*qw);
    const float r20 = 2.f*(qx*qz - qy*qw);
    const float r21 = 2.f*(qy*qz + qx*qw);
    const float r22 = 1.f - 2.f*(qx*qx + qy*qy);

    const float v0 = X[7],  v1 = X[8],  v2 = X[9];
    const float v3 = X[10], v4 = X[11], v5 = X[12];

    // pDot_lin = rot @ v_lin
    xd[0] = r00*v0 + r01*v1 + r02*v2;
    xd[1] = r10*v0 + r11*v1 + r12*v2;
    xd[2] = r20*v0 + r21*v1 + r22*v2;
    // pDot_ang = T(q) @ v_ang,  T = 0.5*[[-x,-y,-z],[w,-z,y],[z,w,-x],[-y,x,w]]
    xd[3] = 0.5f*(-qx*v3 - qy*v4 - qz*v5);
    xd[4] = 0.5f*( qw*v3 - qz*v4 + qy*v5);
    xd[5] = 0.5f*( qz*v3 + qw*v4 - qx*v5);
    xd[6] = 0.5f*(-qy*v3 + qx*v4 + qw*v5);

    const float v[6] = {v0, v1, v2, v3, v4, v5};

    // Dv: D = -linDamp - v_i*linDampFow - quadDamp .* diag(|v|)
    float Dv[6];
#pragma unroll
    for (int i = 0; i < 6; ++i) {
        float s = -c.QD[i] * fabsf(v[i]) * v[i];
#pragma unroll
        for (int j = 0; j < 6; ++j)
            s += (-c.LD[i*6+j] - v[i]*c.LDF[i*6+j]) * v[j];
        Dv[i] = s;
    }

    // Coriolis: mv = M v ; Cv_top = -(mv_top x v_ang)
    //           Cv_bot = -(mv_top x v_lin) - (mv_bot x v_ang)
    float mv[6];
#pragma unroll
    for (int i = 0; i < 6; ++i) {
        float s = 0.f;
#pragma unroll
        for (int j = 0; j < 6; ++j) s += c.M[i*6+j] * v[j];
        mv[i] = s;
    }
    float Cv[6];
    Cv[0] = -(mv[1]*v5 - mv[2]*v4);
    Cv[1] = -(mv[2]*v3 - mv[0]*v5);
    Cv[2] = -(mv[0]*v4 - mv[1]*v3);
    Cv[3] = -(mv[1]*v2 - mv[2]*v1) - (mv[4]*v5 - mv[5]*v4);
    Cv[4] = -(mv[2]*v0 - mv[0]*v2) - (mv[5]*v3 - mv[3]*v5);
    Cv[5] = -(mv[0]*v1 - mv[1]*v0) - (mv[3]*v4 - mv[4]*v3);

    // restoring: fbg = rot^T * (0,0,-m g), fbb = rot^T * (0,0, vol*rho*g)
    const float fgz = -c.mass * 9.81f;
    const float fbz =  c.vol * 1028.0f * 9.81f;
    const float fb0 = r20*fgz, fb1 = r21*fgz, fb2 = r22*fgz;   // fbg
    const float bb0 = r20*fbz, bb1 = r21*fbz, bb2 = r22*fbz;   // fbb
    // mbg + mbb = cog x fbg + cob x fbb
    const float m0 = c.cog[1]*fb2 - c.cog[2]*fb1 + c.cob[1]*bb2 - c.cob[2]*bb1;
    const float m1 = c.cog[2]*fb0 - c.cog[0]*fb2 + c.cob[2]*bb0 - c.cob[0]*bb2;
    const float m2 = c.cog[0]*fb1 - c.cog[1]*fb0 + c.cob[0]*bb1 - c.cob[1]*bb0;
    const float g0 = -(fb0 + bb0), g1 = -(fb1 + bb1), g2 = -(fb2 + bb2);
    const float g3 = -m0, g4 = -m1, g5 = -m2;
    const float gr[6] = {g0, g1, g2, g3, g4, g5};

    float rhs[6];
#pragma unroll
    for (int i = 0; i < 6; ++i) rhs[i] = U[i] - Cv[i] - Dv[i] - gr[i];

    // vDot = Minv @ rhs
#pragma unroll
    for (int i = 0; i < 6; ++i) {
        float s = 0.f;
#pragma unroll
        for (int j = 0; j < 6; ++j) s += c.Mi[i*6+j] * rhs[j];
        xd[7+i] = s;
    }
}

__global__ void __launch_bounds__(256)
auv_rk2(const float* __restrict__ x, const float* __restrict__ u,
        const float* __restrict__ mass, const float* __restrict__ volume,
        const float* __restrict__ cog, const float* __restrict__ cob,
        const float* __restrict__ mTot, const float* __restrict__ linDamp,
        const float* __restrict__ linDampFow, const float* __restrict__ quadDamp,
        const float* __restrict__ minv, float* __restrict__ out, int K)
{
    __shared__ float sx[256 * 13];     // 13312 B
    __shared__ float su[256 * 6];      //  6144 B
    __shared__ SC c;

    const int tid  = threadIdx.x;
    const int base = blockIdx.x * 256;

    // load tiny constants into LDS (one block-broadcast copy)
    if (tid < 36) {
        c.M[tid]   = mTot[tid];
        c.Mi[tid]  = minv[tid];
        c.LD[tid]  = linDamp[tid];
        c.LDF[tid] = linDampFow[tid];
    } else if (tid < 42) {
        const int i = tid - 36;
        c.QD[i] = quadDamp[i*6 + i];
    } else if (tid < 45) {
        const int i = tid - 42;
        c.cog[i] = cog[i];
        c.cob[i] = cob[i];
    } else if (tid == 45) {
        c.mass = mass[0];
        c.vol  = volume[0];
    }

    const int nElem = min(256, K - base);

    if (nElem == 256) {
        // fully-coalesced float4 staging: 256*13 floats = 832 float4
        const float4* gx  = (const float4*)(x + (size_t)base * 13);
        float4*       s4  = (float4*)sx;
        for (int k = tid; k < 832; k += 256) s4[k] = gx[k];
        const float4* gu  = (const float4*)(u + (size_t)base * 6);
        float4*       su4 = (float4*)su;
        for (int k = tid; k < 384; k += 256) su4[k] = gu[k];
    } else {
        for (int k = tid; k < nElem * 13; k += 256) sx[k] = x[(size_t)base*13 + k];
        for (int k = tid; k < nElem * 6;  k += 256) su[k] = u[(size_t)base*6  + k];
    }
    __syncthreads();

    if (tid < nElem) {
        float X[13], U[6];
#pragma unroll
        for (int j = 0; j < 13; ++j) X[j] = sx[tid*13 + j];
#pragma unroll
        for (int j = 0; j < 6;  ++j) U[j] = su[tid*6 + j];

        float k1[13], X2[13], k2[13], Y[13];
        fossen_dot(X, U, c, k1);
#pragma unroll
        for (int j = 0; j < 13; ++j) X2[j] = X[j] + 0.1f * k1[j];
        fossen_dot(X2, U, c, k2);
#pragma unroll
        for (int j = 0; j < 13; ++j) Y[j] = X[j] + 0.05f * (k1[j] + k2[j]);

        // normalize quaternion Y[3..6]
        const float nq = Y[3]*Y[3] + Y[4]*Y[4] + Y[5]*Y[5] + Y[6]*Y[6];
        const float inv = 1.0f / sqrtf(nq);
        Y[3] *= inv; Y[4] *= inv; Y[5] *= inv; Y[6] *= inv;

        // write own row back into sx (disjoint per thread -> no barrier needed)
#pragma unroll
        for (int j = 0; j < 13; ++j) sx[tid*13 + j] = Y[j];
    }
    __syncthreads();

    if (nElem == 256) {
        float4*       go = (float4*)(out + (size_t)base * 13);
        const float4* s4 = (const float4*)sx;
        for (int k = tid; k < 832; k += 256) go[k] = s4[k];
    } else {
        for (int k = tid; k < nElem * 13; k += 256) out[(size_t)base*13 + k] = sx[k];
    }
}

// fp64 Gauss-Jordan 6x6 inversion, one thread; recomputed every launch so the
// kernel does identical work on each call (graph-capture safe, d_ws repoison ok)
__global__ void invert6x6(const float* __restrict__ M, float* __restrict__ Mi)
{
    if (threadIdx.x != 0 || blockIdx.x != 0) return;
    double a[6][12];
    for (int i = 0; i < 6; ++i)
        for (int j = 0; j < 6; ++j) {
            a[i][j]     = (double)M[i*6 + j];
            a[i][6 + j] = (i == j) ? 1.0 : 0.0;
        }
    for (int col = 0; col < 6; ++col) {
        int piv = col;
        double best = fabs(a[col][col]);
        for (int r = col + 1; r < 6; ++r) {
            double vv = fabs(a[r][col]);
            if (vv > best) { best = vv; piv = r; }
        }
        if (piv != col)
            for (int j = 0; j < 12; ++j) {
                double t = a[col][j]; a[col][j] = a[piv][j]; a[piv][j] = t;
            }
        const double d = 1.0 / a[col][col];
        for (int j = 0; j < 12; ++j) a[col][j] *= d;
        for (int r = 0; r < 6; ++r) {
            if (r == col) continue;
            const double f = a[r][col];
            for (int j = 0; j < 12; ++j) a[r][j] -= f * a[col][j];
        }
    }
    for (int i = 0; i < 6; ++i)
        for (int j = 0; j < 6; ++j)
            Mi[i*6 + j] = (float)a[i][6 + j];
}

extern "C" void kernel_launch(void* const* d_in, const int* in_sizes, int n_in,
                              void* d_out, int out_size, void* d_ws, size_t ws_size,
                              hipStream_t stream)
{
    const float* x          = (const float*)d_in[0];
    const float* u          = (const float*)d_in[1];
    const float* mass       = (const float*)d_in[2];
    const float* volume     = (const float*)d_in[3];
    const float* cog        = (const float*)d_in[4];
    const float* cob        = (const float*)d_in[5];
    const float* mTot       = (const float*)d_in[6];
    const float* linDamp    = (const float*)d_in[7];
    const float* linDampFow = (const float*)d_in[8];
    const float* quadDamp   = (const float*)d_in[9];
    float*       out        = (float*)d_out;
    float*       minv       = (float*)d_ws;

    const int K = in_sizes[0] / 13;

    invert6x6<<<1, 64, 0, stream>>>(mTot, minv);

    const int blocks = (K + 255) / 256;
    auv_rk2<<<blocks, 256, 0, stream>>>(x, u, mass, volume, cog, cob, mTot,
                                        linDamp, linDampFow, quadDamp,
                                        minv, out, K);
}

// Round 2
// 117.587 us; speedup vs baseline: 1.1817x; 1.1817x over previous
//
#include <hip/hip_runtime.h>
#include <math.h>

// ---------------------------------------------------------------------------
// AUV Fossen 6-DOF RK2 step, K independent 13-float states.
// R2: (a) invert kernel was 96us due to scratch-resident pivoted GJ -> now
//     fully-unrolled static fp32 GJ (no pivot; mTot diag-dominant).
//     (b) main kernel was LDS-pipe bound (~300 ds_read_b32/thread for the
//     broadcast constants) -> constants now live in a packed const block in
//     d_ws read via uniform literal-index loads (s_load / SGPR broadcast).
// ---------------------------------------------------------------------------

// const-block layout (floats) in d_ws
#define CB_MI   0     // inv(mTot)        36
#define CB_M    36    // mTot             36
#define CB_LD   72    // linDamp          36
#define CB_LDF  108   // linDampFow       36
#define CB_QD   144   // diag(quadDamp)    6
#define CB_COG  150   //                   3
#define CB_COB  153   //                   3
#define CB_MASS 156
#define CB_VOL  157

__device__ __forceinline__ void fossen_dot(const float* __restrict__ X,
                                           const float* __restrict__ U,
                                           const float* __restrict__ cb,
                                           float* __restrict__ xd)
{
    const float qx = X[3], qy = X[4], qz = X[5], qw = X[6];
    const float r00 = 1.f - 2.f*(qy*qy + qz*qz);
    const float r01 = 2.f*(qx*qy - qz*qw);
    const float r02 = 2.f*(qx*qz + qy*qw);
    const float r10 = 2.f*(qx*qy + qz*qw);
    const float r11 = 1.f - 2.f*(qx*qx + qz*qz);
    const float r12 = 2.f*(qy*qz - qx*qw);
    const float r20 = 2.f*(qx*qz - qy*qw);
    const float r21 = 2.f*(qy*qz + qx*qw);
    const float r22 = 1.f - 2.f*(qx*qx + qy*qy);

    const float v0 = X[7],  v1 = X[8],  v2 = X[9];
    const float v3 = X[10], v4 = X[11], v5 = X[12];

    xd[0] = r00*v0 + r01*v1 + r02*v2;
    xd[1] = r10*v0 + r11*v1 + r12*v2;
    xd[2] = r20*v0 + r21*v1 + r22*v2;
    xd[3] = 0.5f*(-qx*v3 - qy*v4 - qz*v5);
    xd[4] = 0.5f*( qw*v3 - qz*v4 + qy*v5);
    xd[5] = 0.5f*( qz*v3 + qw*v4 - qx*v5);
    xd[6] = 0.5f*(-qy*v3 + qx*v4 + qw*v5);

    const float v[6] = {v0, v1, v2, v3, v4, v5};

    // P = -Dv : P_i = (LD v)_i + v_i (LDF v)_i + QD_i |v_i| v_i
    float P[6];
#pragma unroll
    for (int i = 0; i < 6; ++i) {
        float ld = 0.f, ldf = 0.f;
#pragma unroll
        for (int j = 0; j < 6; ++j) {
            ld  += cb[CB_LD  + i*6 + j] * v[j];
            ldf += cb[CB_LDF + i*6 + j] * v[j];
        }
        P[i] = ld + v[i]*ldf + cb[CB_QD + i] * fabsf(v[i]) * v[i];
    }

    // Coriolis via mv = M v, cross products
    float mv[6];
#pragma unroll
    for (int i = 0; i < 6; ++i) {
        float s = 0.f;
#pragma unroll
        for (int j = 0; j < 6; ++j) s += cb[CB_M + i*6 + j] * v[j];
        mv[i] = s;
    }
    float Cv[6];
    Cv[0] = -(mv[1]*v5 - mv[2]*v4);
    Cv[1] = -(mv[2]*v3 - mv[0]*v5);
    Cv[2] = -(mv[0]*v4 - mv[1]*v3);
    Cv[3] = -(mv[1]*v2 - mv[2]*v1) - (mv[4]*v5 - mv[5]*v4);
    Cv[4] = -(mv[2]*v0 - mv[0]*v2) - (mv[5]*v3 - mv[3]*v5);
    Cv[5] = -(mv[0]*v1 - mv[1]*v0) - (mv[3]*v4 - mv[4]*v3);

    // restoring (uses only row 2 of rot)
    const float fgz = -cb[CB_MASS] * 9.81f;
    const float fbz =  cb[CB_VOL] * 1028.0f * 9.81f;
    const float fb0 = r20*fgz, fb1 = r21*fgz, fb2 = r22*fgz;
    const float bb0 = r20*fbz, bb1 = r21*fbz, bb2 = r22*fbz;
    const float cgx = cb[CB_COG], cgy = cb[CB_COG+1], cgz = cb[CB_COG+2];
    const float cbx = cb[CB_COB], cby = cb[CB_COB+1], cbz = cb[CB_COB+2];
    const float m0 = cgy*fb2 - cgz*fb1 + cby*bb2 - cbz*bb1;
    const float m1 = cgz*fb0 - cgx*fb2 + cbz*bb0 - cbx*bb2;
    const float m2 = cgx*fb1 - cgy*fb0 + cbx*bb1 - cby*bb0;
    const float g[6] = { -(fb0+bb0), -(fb1+bb1), -(fb2+bb2), -m0, -m1, -m2 };

    float rhs[6];
#pragma unroll
    for (int i = 0; i < 6; ++i) rhs[i] = U[i] - Cv[i] + P[i] - g[i];

#pragma unroll
    for (int i = 0; i < 6; ++i) {
        float s = 0.f;
#pragma unroll
        for (int j = 0; j < 6; ++j) s += cb[CB_MI + i*6 + j] * rhs[j];
        xd[7+i] = s;
    }
}

__global__ void __launch_bounds__(256)
auv_rk2(const float* __restrict__ x, const float* __restrict__ u,
        const float* __restrict__ cb, float* __restrict__ out, int K)
{
    __shared__ float sx[256 * 13];     // 13312 B, packed rows of 13
    const int tid  = threadIdx.x;
    const int base = blockIdx.x * 256;
    const int nElem = min(256, K - base);

    if (nElem == 256) {
        // async global->LDS staging, width 16, lane-contiguous mapping
        const float* gx = x + (size_t)base * 13;
#pragma unroll
        for (int it = 0; it < 3; ++it) {
            const int k = it*256 + tid;       // float4 index
            __builtin_amdgcn_global_load_lds(
                (const __attribute__((address_space(1))) void*)(gx + (size_t)k*4),
                (__attribute__((address_space(3))) void*)(&sx[k*4]), 16, 0, 0);
        }
        if (tid < 64) {
            const int k = 768 + tid;
            __builtin_amdgcn_global_load_lds(
                (const __attribute__((address_space(1))) void*)(gx + (size_t)k*4),
                (__attribute__((address_space(3))) void*)(&sx[k*4]), 16, 0, 0);
        }
    } else {
        for (int k = tid; k < nElem*13; k += 256) sx[k] = x[(size_t)base*13 + k];
    }

    // u direct: 24B/row, 8B-aligned -> 3x float2 per thread
    float U[6];
    if (tid < nElem) {
        const float* gu = u + (size_t)(base + tid) * 6;
        const float2 a = *(const float2*)(gu);
        const float2 b = *(const float2*)(gu + 2);
        const float2 c = *(const float2*)(gu + 4);
        U[0]=a.x; U[1]=a.y; U[2]=b.x; U[3]=b.y; U[4]=c.x; U[5]=c.y;
    }
    __syncthreads();   // drains global_load_lds (vmcnt) + cross-wave visibility

    if (tid < nElem) {
        float X[13];
#pragma unroll
        for (int j = 0; j < 13; ++j) X[j] = sx[tid*13 + j];

        float k1[13], X2[13], k2[13], Y[13];
        fossen_dot(X, U, cb, k1);
#pragma unroll
        for (int j = 0; j < 13; ++j) X2[j] = X[j] + 0.1f * k1[j];
        fossen_dot(X2, U, cb, k2);
#pragma unroll
        for (int j = 0; j < 13; ++j) Y[j] = X[j] + 0.05f * (k1[j] + k2[j]);

        const float nq  = Y[3]*Y[3] + Y[4]*Y[4] + Y[5]*Y[5] + Y[6]*Y[6];
        const float inv = 1.0f / sqrtf(nq);
        Y[3] *= inv; Y[4] *= inv; Y[5] *= inv; Y[6] *= inv;

        // own-row write; no pre-barrier needed (each thread touches only row tid)
#pragma unroll
        for (int j = 0; j < 13; ++j) sx[tid*13 + j] = Y[j];
    }
    __syncthreads();

    if (nElem == 256) {
        float4*       go = (float4*)(out + (size_t)base * 13);
        const float4* s4 = (const float4*)sx;
#pragma unroll
        for (int it = 0; it < 3; ++it) go[it*256 + tid] = s4[it*256 + tid];
        if (tid < 64) go[768 + tid] = s4[768 + tid];
    } else {
        for (int k = tid; k < nElem*13; k += 256) out[(size_t)base*13 + k] = sx[k];
    }
}

// Pack constants into cb[158] and invert mTot.
// Fully-unrolled static-index fp32 Gauss-Jordan, NO pivoting (mTot ~ 200*I,
// diagonally dominant; reference solve is fp32 too). Everything stays in
// registers -> no scratch traffic (R1's 96us bug).
__global__ void prep_consts(const float* __restrict__ mass,
                            const float* __restrict__ volume,
                            const float* __restrict__ cog,
                            const float* __restrict__ cob,
                            const float* __restrict__ mTot,
                            const float* __restrict__ linDamp,
                            const float* __restrict__ linDampFow,
                            const float* __restrict__ quadDamp,
                            float* __restrict__ cb)
{
    const int t = threadIdx.x;
    if (t < 36) {
        cb[CB_M   + t] = mTot[t];
        cb[CB_LD  + t] = linDamp[t];
        cb[CB_LDF + t] = linDampFow[t];
    }
    if (t < 6)  cb[CB_QD + t] = quadDamp[t*6 + t];
    if (t < 3)  { cb[CB_COG + t] = cog[t]; cb[CB_COB + t] = cob[t]; }
    if (t == 0) { cb[CB_MASS] = mass[0]; cb[CB_VOL] = volume[0]; }

    if (t == 0) {
        float a[36], inv[36];
#pragma unroll
        for (int i = 0; i < 36; ++i) a[i] = mTot[i];
#pragma unroll
        for (int i = 0; i < 36; ++i) inv[i] = 0.f;
#pragma unroll
        for (int i = 0; i < 6; ++i) inv[i*6 + i] = 1.f;
#pragma unroll
        for (int col = 0; col < 6; ++col) {
            const float d = 1.0f / a[col*6 + col];
#pragma unroll
            for (int j = 0; j < 6; ++j) { a[col*6+j] *= d; inv[col*6+j] *= d; }
#pragma unroll
            for (int r = 0; r < 6; ++r) {
                if (r == col) continue;
                const float f = a[r*6 + col];
#pragma unroll
                for (int j = 0; j < 6; ++j) {
                    a[r*6+j]   -= f * a[col*6+j];
                    inv[r*6+j] -= f * inv[col*6+j];
                }
            }
        }
#pragma unroll
        for (int i = 0; i < 36; ++i) cb[CB_MI + i] = inv[i];
    }
}

extern "C" void kernel_launch(void* const* d_in, const int* in_sizes, int n_in,
                              void* d_out, int out_size, void* d_ws, size_t ws_size,
                              hipStream_t stream)
{
    const float* x          = (const float*)d_in[0];
    const float* u          = (const float*)d_in[1];
    const float* mass       = (const float*)d_in[2];
    const float* volume     = (const float*)d_in[3];
    const float* cog        = (const float*)d_in[4];
    const float* cob        = (const float*)d_in[5];
    const float* mTot       = (const float*)d_in[6];
    const float* linDamp    = (const float*)d_in[7];
    const float* linDampFow = (const float*)d_in[8];
    const float* quadDamp   = (const float*)d_in[9];
    float*       out        = (float*)d_out;
    float*       cb         = (float*)d_ws;

    const int K = in_sizes[0] / 13;

    prep_consts<<<1, 64, 0, stream>>>(mass, volume, cog, cob, mTot,
                                      linDamp, linDampFow, quadDamp, cb);

    const int blocks = (K + 255) / 256;
    auv_rk2<<<blocks, 256, 0, stream>>>(x, u, cb, out, K);
}

// Round 3
// 113.511 us; speedup vs baseline: 1.2241x; 1.0359x over previous
//
#include <hip/hip_runtime.h>
#include <math.h>

// ---------------------------------------------------------------------------
// AUV Fossen 6-DOF RK2 step, K independent 13-float states. Single fused
// kernel: the 6x6 inv(mTot) is recomputed per-thread from uniform scalar
// loads (fully-unrolled static-index fp32 Gauss-Jordan, ~440 VALU ops that
// overlap the global->LDS staging), eliminating the prep kernel + graph node.
// Memory floor: 128 B/elem -> ~67 MB, ~11 us at achievable HBM BW.
// ---------------------------------------------------------------------------

__device__ __forceinline__ void fossen_dot(const float* __restrict__ X,
                                           const float* __restrict__ U,
                                           const float* __restrict__ Mi,   // regs
                                           const float* __restrict__ mTot, // s_load
                                           const float* __restrict__ linDamp,
                                           const float* __restrict__ linDampFow,
                                           const float* __restrict__ qdiag, // regs[6]
                                           const float* __restrict__ cgcb,  // regs[6]
                                           float fgz, float fbz,
                                           float* __restrict__ xd)
{
    const float qx = X[3], qy = X[4], qz = X[5], qw = X[6];
    const float r00 = 1.f - 2.f*(qy*qy + qz*qz);
    const float r01 = 2.f*(qx*qy - qz*qw);
    const float r02 = 2.f*(qx*qz + qy*qw);
    const float r10 = 2.f*(qx*qy + qz*qw);
    const float r11 = 1.f - 2.f*(qx*qx + qz*qz);
    const float r12 = 2.f*(qy*qz - qx*qw);
    const float r20 = 2.f*(qx*qz - qy*qw);
    const float r21 = 2.f*(qy*qz + qx*qw);
    const float r22 = 1.f - 2.f*(qx*qx + qy*qy);

    const float v0 = X[7],  v1 = X[8],  v2 = X[9];
    const float v3 = X[10], v4 = X[11], v5 = X[12];

    xd[0] = r00*v0 + r01*v1 + r02*v2;
    xd[1] = r10*v0 + r11*v1 + r12*v2;
    xd[2] = r20*v0 + r21*v1 + r22*v2;
    xd[3] = 0.5f*(-qx*v3 - qy*v4 - qz*v5);
    xd[4] = 0.5f*( qw*v3 - qz*v4 + qy*v5);
    xd[5] = 0.5f*( qz*v3 + qw*v4 - qx*v5);
    xd[6] = 0.5f*(-qy*v3 + qx*v4 + qw*v5);

    const float v[6] = {v0, v1, v2, v3, v4, v5};

    // P = -Dv : P_i = (LD v)_i + v_i (LDF v)_i + QD_i |v_i| v_i
    float P[6];
#pragma unroll
    for (int i = 0; i < 6; ++i) {
        float ld = 0.f, ldf = 0.f;
#pragma unroll
        for (int j = 0; j < 6; ++j) {
            ld  += linDamp[i*6 + j]    * v[j];
            ldf += linDampFow[i*6 + j] * v[j];
        }
        P[i] = ld + v[i]*ldf + qdiag[i] * fabsf(v[i]) * v[i];
    }

    // Coriolis via mv = M v, then cross products (skew(a)b = a x b)
    float mv[6];
#pragma unroll
    for (int i = 0; i < 6; ++i) {
        float s = 0.f;
#pragma unroll
        for (int j = 0; j < 6; ++j) s += mTot[i*6 + j] * v[j];
        mv[i] = s;
    }
    float Cv[6];
    Cv[0] = -(mv[1]*v5 - mv[2]*v4);
    Cv[1] = -(mv[2]*v3 - mv[0]*v5);
    Cv[2] = -(mv[0]*v4 - mv[1]*v3);
    Cv[3] = -(mv[1]*v2 - mv[2]*v1) - (mv[4]*v5 - mv[5]*v4);
    Cv[4] = -(mv[2]*v0 - mv[0]*v2) - (mv[5]*v3 - mv[3]*v5);
    Cv[5] = -(mv[0]*v1 - mv[1]*v0) - (mv[3]*v4 - mv[4]*v3);

    // restoring (only row 2 of rot enters)
    const float fb0 = r20*fgz, fb1 = r21*fgz, fb2 = r22*fgz;
    const float bb0 = r20*fbz, bb1 = r21*fbz, bb2 = r22*fbz;
    const float cgx = cgcb[0], cgy = cgcb[1], cgz = cgcb[2];
    const float cbx = cgcb[3], cby = cgcb[4], cbz = cgcb[5];
    const float m0 = cgy*fb2 - cgz*fb1 + cby*bb2 - cbz*bb1;
    const float m1 = cgz*fb0 - cgx*fb2 + cbz*bb0 - cbx*bb2;
    const float m2 = cgx*fb1 - cgy*fb0 + cbx*bb1 - cby*bb0;
    const float g[6] = { -(fb0+bb0), -(fb1+bb1), -(fb2+bb2), -m0, -m1, -m2 };

    float rhs[6];
#pragma unroll
    for (int i = 0; i < 6; ++i) rhs[i] = U[i] - Cv[i] + P[i] - g[i];

    // vDot = Minv @ rhs   (Minv in VGPRs, computed once per thread)
#pragma unroll
    for (int i = 0; i < 6; ++i) {
        float s = 0.f;
#pragma unroll
        for (int j = 0; j < 6; ++j) s += Mi[i*6 + j] * rhs[j];
        xd[7+i] = s;
    }
}

__global__ void __launch_bounds__(256)
auv_rk2_fused(const float* __restrict__ x, const float* __restrict__ u,
              const float* __restrict__ mass, const float* __restrict__ volume,
              const float* __restrict__ cog, const float* __restrict__ cob,
              const float* __restrict__ mTot, const float* __restrict__ linDamp,
              const float* __restrict__ linDampFow,
              const float* __restrict__ quadDamp,
              float* __restrict__ out, int K)
{
    __shared__ float sx[256 * 13];     // 13312 B, packed rows of 13 floats
    const int tid   = threadIdx.x;
    const int base  = blockIdx.x * 256;
    const int nElem = min(256, K - base);

    // ---- issue async global->LDS staging first (no VGPR round-trip) ----
    if (nElem == 256) {
        const float* gx = x + (size_t)base * 13;
#pragma unroll
        for (int it = 0; it < 3; ++it) {
            const int k = it*256 + tid;       // float4 index
            __builtin_amdgcn_global_load_lds(
                (const __attribute__((address_space(1))) void*)(gx + (size_t)k*4),
                (__attribute__((address_space(3))) void*)(&sx[k*4]), 16, 0, 0);
        }
        if (tid < 64) {
            const int k = 768 + tid;
            __builtin_amdgcn_global_load_lds(
                (const __attribute__((address_space(1))) void*)(gx + (size_t)k*4),
                (__attribute__((address_space(3))) void*)(&sx[k*4]), 16, 0, 0);
        }
    } else {
        for (int k = tid; k < nElem*13; k += 256) sx[k] = x[(size_t)base*13 + k];
    }

    // u direct: 24 B/row, 8 B-aligned -> 3x float2 per thread (overlaps LDS DMA)
    float U[6];
    if (tid < nElem) {
        const float* gu = u + (size_t)(base + tid) * 6;
        const float2 a2 = *(const float2*)(gu);
        const float2 b2 = *(const float2*)(gu + 2);
        const float2 c2 = *(const float2*)(gu + 4);
        U[0]=a2.x; U[1]=a2.y; U[2]=b2.x; U[3]=b2.y; U[4]=c2.x; U[5]=c2.y;
    }

    // ---- per-thread (uniform) constants; overlaps the in-flight staging ----
    float qdiag[6], cgcb[6];
#pragma unroll
    for (int i = 0; i < 6; ++i) qdiag[i] = quadDamp[i*6 + i];
#pragma unroll
    for (int i = 0; i < 3; ++i) { cgcb[i] = cog[i]; cgcb[3+i] = cob[i]; }
    const float fgz = -mass[0] * 9.81f;
    const float fbz =  volume[0] * 1028.0f * 9.81f;

    // inv(mTot): fully-unrolled static-index fp32 Gauss-Jordan, no pivot
    // (mTot is diagonally dominant; validated vs reference in R2). All
    // indices are compile-time -> registers only, ~440 VALU ops, uniform.
    float Mi[36];
    {
        float a[36];
#pragma unroll
        for (int i = 0; i < 36; ++i) a[i] = mTot[i];
#pragma unroll
        for (int i = 0; i < 36; ++i) Mi[i] = 0.f;
#pragma unroll
        for (int i = 0; i < 6; ++i) Mi[i*6 + i] = 1.f;
#pragma unroll
        for (int col = 0; col < 6; ++col) {
            const float d = 1.0f / a[col*6 + col];
#pragma unroll
            for (int j = 0; j < 6; ++j) { a[col*6+j] *= d; Mi[col*6+j] *= d; }
#pragma unroll
            for (int r = 0; r < 6; ++r) {
                if (r == col) continue;
                const float f = a[r*6 + col];
#pragma unroll
                for (int j = 0; j < 6; ++j) {
                    a[r*6+j]  -= f * a[col*6+j];
                    Mi[r*6+j] -= f * Mi[col*6+j];
                }
            }
        }
    }

    __syncthreads();   // drains global_load_lds + cross-wave visibility

    if (tid < nElem) {
        float X[13];
#pragma unroll
        for (int j = 0; j < 13; ++j) X[j] = sx[tid*13 + j];

        float k1[13], X2[13], k2[13], Y[13];
        fossen_dot(X, U, Mi, mTot, linDamp, linDampFow, qdiag, cgcb, fgz, fbz, k1);
#pragma unroll
        for (int j = 0; j < 13; ++j) X2[j] = X[j] + 0.1f * k1[j];
        fossen_dot(X2, U, Mi, mTot, linDamp, linDampFow, qdiag, cgcb, fgz, fbz, k2);
#pragma unroll
        for (int j = 0; j < 13; ++j) Y[j] = X[j] + 0.05f * (k1[j] + k2[j]);

        const float nq  = Y[3]*Y[3] + Y[4]*Y[4] + Y[5]*Y[5] + Y[6]*Y[6];
        const float inv = 1.0f / sqrtf(nq);
        Y[3] *= inv; Y[4] *= inv; Y[5] *= inv; Y[6] *= inv;

        // own-row write-back (disjoint rows -> no barrier needed before)
#pragma unroll
        for (int j = 0; j < 13; ++j) sx[tid*13 + j] = Y[j];
    }
    __syncthreads();

    if (nElem == 256) {
        float4*       go = (float4*)(out + (size_t)base * 13);
        const float4* s4 = (const float4*)sx;
#pragma unroll
        for (int it = 0; it < 3; ++it) go[it*256 + tid] = s4[it*256 + tid];
        if (tid < 64) go[768 + tid] = s4[768 + tid];
    } else {
        for (int k = tid; k < nElem*13; k += 256) out[(size_t)base*13 + k] = sx[k];
    }
}

extern "C" void kernel_launch(void* const* d_in, const int* in_sizes, int n_in,
                              void* d_out, int out_size, void* d_ws, size_t ws_size,
                              hipStream_t stream)
{
    const float* x          = (const float*)d_in[0];
    const float* u          = (const float*)d_in[1];
    const float* mass       = (const float*)d_in[2];
    const float* volume     = (const float*)d_in[3];
    const float* cog        = (const float*)d_in[4];
    const float* cob        = (const float*)d_in[5];
    const float* mTot       = (const float*)d_in[6];
    const float* linDamp    = (const float*)d_in[7];
    const float* linDampFow = (const float*)d_in[8];
    const float* quadDamp   = (const float*)d_in[9];
    float*       out        = (float*)d_out;

    const int K = in_sizes[0] / 13;
    const int blocks = (K + 255) / 256;
    auv_rk2_fused<<<blocks, 256, 0, stream>>>(x, u, mass, volume, cog, cob,
                                              mTot, linDamp, linDampFow,
                                              quadDamp, out, K);
}